// Round 2
// 117.750 us; speedup vs baseline: 1.1638x; 1.1638x over previous
//
#include <hip/hip_runtime.h>
#include <stdint.h>
#include <math.h>

// Problem constants (B=8192 rows, D=512 features)
#define Bn 8192
#define Dn 512
#define EPSN 1e-12f
#define EPSP 1e-6f
#define MARG 0.3f

// R19 = R18 resubmitted (round 1 bench was an infra failure: "MI355X
// container failed twice", no counters, no verdict - source re-audited, no
// change). R18 vs R17:
// (1) The argmax INDEX is dead code (K3 only uses the max SCORE; ties give
//     identical scores) -> u64 (score,idx) pack replaced by a monotonic u32
//     float key. atomicMax over u32 keys = exact float max, deterministic.
// (2) MFMA operands SWAPPED (As<-p rows, Bs<-a rows) so acc holds C^T: each
//     lane owns 16 in-lane candidates (mt,v = j-direction) per output row i
//     (m16 = col). Row-reduce = in-register fmaxf chain (v_max3) + TWO u32
//     shuffle steps (q-groups, masks 16/32) instead of FOUR u64 steps.
//     Per-element epilogue: ~11 VALU ops + 2 u64 swizzles -> ~3 VALU ops.
//     c[j] folded in per-lane via 4 broadcast float4 loads (L2-resident).
// (3) Diagonal mask only on the 64 diagonal blocks (wave-uniform branch).
// GEMM core byte-identical to R11..R17 (i8 16x16x64, 0 conflicts, absmax 0.0
// across 6 rounds) - only the As/Bs source arrays swap.
// Ledger: occupancy lever exhausted (R2/R5/R6), B-out-of-LDS loses (R4/R7),
// fp8 mfma_scale spills (R9), i8 2xK wins (R11), transposed/packed partials
// kill write amplification (R14/R15), algebraic neg^2 kills K3's gather
// (R16), single-address atomics +100us (R5), ticket+fence +20us (R10),
// cooperative launch no-ops under graph capture (R12), K2 is epilogue-
// VALU-bound not MFMA/HBM-bound (R17 counters: MfmaUtil 17, VALU 35, HBM 4%).
#define BM 128
#define BN 128
#define BKB 64          // k elements (=bytes) per tile
#define KT (Dn / BKB)   // 8 k-iterations
#define NCT (Bn / BN)   // 64 column tiles
#define QS 256.0f
#define ISQ (2.0f / 65536.0f)

typedef int   int4v __attribute__((ext_vector_type(4)));
typedef float f32x4 __attribute__((ext_vector_type(4)));

// async global->LDS, 16B per lane; LDS dest is wave-uniform base + lane*16
__device__ __forceinline__ void async16(const void* g, void* l) {
    __builtin_amdgcn_global_load_lds(
        (const __attribute__((address_space(1))) void*)g,
        (__attribute__((address_space(3))) void*)l,
        16, 0, 0);
}

// monotonic float->u32 key: key(a) > key(b) iff a > b (finite floats).
// Any finite score's key is nonzero, so 0 is the atomicMax identity.
__device__ __forceinline__ unsigned key32(float s) {
    union { float f; unsigned u; } c; c.f = s;
    return (c.u & 0x80000000u) ? ~c.u : (c.u | 0x80000000u);
}
__device__ __forceinline__ float unkey32(unsigned k) {
    union { unsigned u; float f; } c;
    c.u = (k & 0x80000000u) ? (k ^ 0x80000000u) : ~k;
    return c.f;
}

// ---------------------------------------------------------------------------
// K1: one wave per row pair (a_i, p_i): L2-normalize both -> i8 rows (x256,
// RNE, clamp +-127), column term c[j] = -sp2[j] + 2*eps*sp[j], rowconst[i] =
// pos2 - sa2 - 2*eps*sa - D*eps^2 + MARGIN (exact fp32), and rowmax[i] = 0.
// 2048 blocks; at the HBM floor (~40 MB moved).
// ---------------------------------------------------------------------------
__global__ __launch_bounds__(256) void k_normalize(
    const float* __restrict__ x,
    uint8_t* __restrict__ a_i8, uint8_t* __restrict__ p_i8,
    float* __restrict__ cterm, float* __restrict__ rowconst,
    unsigned* __restrict__ rowmax)
{
    const int wave = threadIdx.x >> 6;
    const int lane = threadIdx.x & 63;
    const int i = blockIdx.x * 4 + wave;   // 0..8191

    const float* srcA = x + (size_t)i * (2 * Dn) + lane * 8;
    const float* srcP = srcA + Dn;
    float4 a0 = ((const float4*)srcA)[0];
    float4 a1 = ((const float4*)srcA)[1];
    float4 p0 = ((const float4*)srcP)[0];
    float4 p1 = ((const float4*)srcP)[1];
    float va[8] = {a0.x, a0.y, a0.z, a0.w, a1.x, a1.y, a1.z, a1.w};
    float vp[8] = {p0.x, p0.y, p0.z, p0.w, p1.x, p1.y, p1.z, p1.w};

    float ssa = 0.f, ssp = 0.f;
#pragma unroll
    for (int j = 0; j < 8; ++j) { ssa += va[j] * va[j]; ssp += vp[j] * vp[j]; }
#pragma unroll
    for (int m = 1; m < 64; m <<= 1) {
        ssa += __shfl_xor(ssa, m);
        ssp += __shfl_xor(ssp, m);
    }
    const float sa = 1.0f / fmaxf(sqrtf(ssa), EPSN);
    const float sp = 1.0f / fmaxf(sqrtf(ssp), EPSN);

    float oa[8], op[8];
    float s1p = 0.f, s2p = 0.f, s1a = 0.f, s2a = 0.f, pos = 0.f;
#pragma unroll
    for (int j = 0; j < 8; ++j) {
        oa[j] = va[j] * sa;
        op[j] = vp[j] * sp;
        s1p += op[j]; s2p += op[j] * op[j];
        s1a += oa[j]; s2a += oa[j] * oa[j];
        const float u = oa[j] - op[j] + EPSP;
        pos += u * u;
    }

    uint64_t pka = 0, pkp = 0;
#pragma unroll
    for (int j = 0; j < 8; ++j) {
        int qa = (int)rintf(oa[j] * QS);
        int qp = (int)rintf(op[j] * QS);
        qa = qa > 127 ? 127 : (qa < -127 ? -127 : qa);
        qp = qp > 127 ? 127 : (qp < -127 ? -127 : qp);
        pka |= (uint64_t)(uint8_t)qa << (8 * j);
        pkp |= (uint64_t)(uint8_t)qp << (8 * j);
    }
    *(uint64_t*)(a_i8 + (size_t)i * Dn + lane * 8) = pka;
    *(uint64_t*)(p_i8 + (size_t)i * Dn + lane * 8) = pkp;

#pragma unroll
    for (int m = 1; m < 64; m <<= 1) {
        s1p += __shfl_xor(s1p, m);
        s2p += __shfl_xor(s2p, m);
        s1a += __shfl_xor(s1a, m);
        s2a += __shfl_xor(s2a, m);
        pos += __shfl_xor(pos, m);
    }
    if (lane == 0) {
        cterm[i] = -s2p + 2.0f * EPSP * s1p;
        rowconst[i] = pos - s2a - 2.0f * EPSP * s1a
                      - (float)Dn * EPSP * EPSP + MARG;
        rowmax[i] = 0u;              // atomicMax identity (poisoned otherwise)
    }
}

// ---------------------------------------------------------------------------
// K2: i8 MFMA GEMM with SWAPPED operands (p_n @ a_n^T -> acc holds C^T) +
// fused per-i max. K-loop byte-identical to R11..R17. Epilogue: per lane,
// in-register fmax over the 16 j-candidates (mt,v) per output row i, two
// u32 shuffle steps across q-groups, LDS combine of the two j-half waves,
// ONE u32 atomicMax per (block,row).
// ---------------------------------------------------------------------------
__global__ __launch_bounds__(256, 4) void k_gemm_argmax(
    const uint8_t* __restrict__ a_i8, const uint8_t* __restrict__ p_i8,
    const float* __restrict__ cterm,
    unsigned* __restrict__ rowmax)
{
    __shared__ uint8_t As[2][BM * BKB];   // 2 x 8 KB  (p rows: j-direction)
    __shared__ uint8_t Bs[2][BN * BKB];   // 2 x 8 KB  (a rows: i-direction)
    __shared__ unsigned sm[2][BN];        // per-j-half, per-i block max

    const int t = threadIdx.x;
    const int wave = t >> 6;
    const int lane = t & 63;
    const int rowBase = blockIdx.y * BM;   // j base (p rows)
    const int colBase = blockIdx.x * BN;   // i base (a rows)

    const int q = lane >> 4;       // 0..3  (k-chunk; C/D row = q*4+v)
    const int m16 = lane & 15;     // 0..15 (C/D col)
    const int waveRow = (wave >> 1) * 64;  // j partition
    const int waveCol = (wave & 1) * 64;   // i partition

    // staging pointers, hoisted (chunk c -> row c>>2, slot c&3 holds global
    // k-chunk (c&3)^((row>>1)&3))
    const int r0 = t >> 2;
    const int g0 = (t & 3) ^ ((r0 >> 1) & 3);
    const int r1 = (256 + t) >> 2;
    const int g1 = ((256 + t) & 3) ^ ((r1 >> 1) & 3);
    const uint8_t* gA0 = p_i8 + (size_t)(rowBase + r0) * Dn + g0 * 16;  // SWAP
    const uint8_t* gA1 = p_i8 + (size_t)(rowBase + r1) * Dn + g1 * 16;
    const uint8_t* gB0 = a_i8 + (size_t)(colBase + r0) * Dn + g0 * 16;  // SWAP
    const uint8_t* gB1 = a_i8 + (size_t)(colBase + r1) * Dn + g1 * 16;
    const int ldsC0 = (wave * 64) * 16;          // bytes; HW adds lane*16
    const int ldsC1 = (256 + wave * 64) * 16;

    // fragment LDS read bases: slot = q ^ ((m16>>1)&3) for ALL mt/nt
    const int s0 = q ^ ((m16 >> 1) & 3);
    const int aBase = (waveRow + m16) * BKB + s0 * 16;   // bytes
    const int bBase = (waveCol + m16) * BKB + s0 * 16;

    int4v acc[4][4];
#pragma unroll
    for (int a = 0; a < 4; ++a)
#pragma unroll
        for (int b = 0; b < 4; ++b) acc[a][b] = (int4v){0, 0, 0, 0};

    auto stage = [&](int buf, int ke) {      // ke = byte offset kt*64
        async16(gA0 + ke, &As[buf][ldsC0]);
        async16(gA1 + ke, &As[buf][ldsC1]);
        async16(gB0 + ke, &Bs[buf][ldsC0]);
        async16(gB1 + ke, &Bs[buf][ldsC1]);
    };

    stage(0, 0);
#pragma unroll
    for (int kt = 0; kt < KT; ++kt) {
        const int cur = kt & 1;
        __syncthreads();                 // tile kt resident; prior buf reads done
        if (kt + 1 < KT) stage(cur ^ 1, (kt + 1) * BKB);  // drains at NEXT barrier

        const uint8_t* pa = &As[cur][aBase];
        const uint8_t* pb = &Bs[cur][bBase];
        int4v af[4], bfr[4];
#pragma unroll
        for (int mt = 0; mt < 4; ++mt)
            af[mt] = *(const int4v*)(pa + mt * 16 * BKB);
#pragma unroll
        for (int nt = 0; nt < 4; ++nt)
            bfr[nt] = *(const int4v*)(pb + nt * 16 * BKB);
#pragma unroll
        for (int mt = 0; mt < 4; ++mt)
#pragma unroll
            for (int nt = 0; nt < 4; ++nt)
                acc[mt][nt] = __builtin_amdgcn_mfma_i32_16x16x64_i8(
                    af[mt], bfr[nt], acc[mt][nt], 0, 0, 0);
    }

    // ---- epilogue: acc[mt][nt][v] = idot(j, i) with
    //   j = rowBase + waveRow + mt*16 + q*4 + v   (16 in-lane candidates)
    //   i = colBase + waveCol + nt*16 + m16       (4 rows per lane)
    // score = ISQ*idot + c[j]; per-i max is an in-lane fmax chain.
    f32x4 cj[4];
#pragma unroll
    for (int mt = 0; mt < 4; ++mt)   // broadcast loads, L2-resident 32 KB
        cj[mt] = *(const f32x4*)(cterm + rowBase + waveRow + mt * 16 + q * 4);

    unsigned kv[4];
    const bool diag = (rowBase == colBase);   // 64 of 4096 blocks
    if (!diag) {
#pragma unroll
        for (int nt = 0; nt < 4; ++nt) {
            float mx = -3.4e38f;
#pragma unroll
            for (int mt = 0; mt < 4; ++mt)
#pragma unroll
                for (int v = 0; v < 4; ++v)
                    mx = fmaxf(mx, ISQ * (float)acc[mt][nt][v] + cj[mt][v]);
            kv[nt] = key32(mx);
        }
    } else {
#pragma unroll
        for (int nt = 0; nt < 4; ++nt) {
            // j==i  <=>  mt*16+v == dtarget  (at most one of the 16)
            const int dtarget = waveCol - waveRow + nt * 16 + m16 - q * 4;
            float mx = -3.4e38f;
#pragma unroll
            for (int mt = 0; mt < 4; ++mt)
#pragma unroll
                for (int v = 0; v < 4; ++v) {
                    const float sc = ISQ * (float)acc[mt][nt][v] + cj[mt][v];
                    mx = (mt * 16 + v == dtarget) ? mx : fmaxf(mx, sc);
                }
            kv[nt] = key32(mx);
        }
    }

    // combine the 4 q-groups (same i, different j): masks 16, 32
#pragma unroll
    for (int nt = 0; nt < 4; ++nt) {
#pragma unroll
        for (int msk = 16; msk < 64; msk <<= 1) {
            const unsigned o = (unsigned)__shfl_xor((int)kv[nt], msk);
            kv[nt] = o > kv[nt] ? o : kv[nt];
        }
    }
    if (lane < 16) {   // q==0 lanes hold the reduced keys
#pragma unroll
        for (int nt = 0; nt < 4; ++nt)
            sm[wave >> 1][(wave & 1) * 64 + nt * 16 + m16] = kv[nt];
    }
    __syncthreads();
    if (t < BN) {
        const unsigned k0 = sm[0][t];
        const unsigned k1 = sm[1][t];
        // distributed per-row max: 64 blocks contend per address (order-
        // independent -> deterministic), 8192 addresses total.
        atomicMax(&rowmax[colBase + t], k0 > k1 ? k0 : k1);
    }
}

// ---------------------------------------------------------------------------
// K3: single block - loss = mean(relu(rowconst[i] + score_max[i])).
// Reads 64 KB; deterministic fixed-order sums.
// ---------------------------------------------------------------------------
__global__ __launch_bounds__(1024) void k_final(
    const unsigned* __restrict__ rowmax,
    const float* __restrict__ rowconst,
    float* __restrict__ out)
{
    __shared__ float smf[16];
    float s = 0.f;
    for (int k = threadIdx.x; k < Bn; k += 1024)
        s += fmaxf(rowconst[k] + unkey32(rowmax[k]), 0.f);
#pragma unroll
    for (int msk = 1; msk < 64; msk <<= 1) s += __shfl_xor(s, msk);
    if ((threadIdx.x & 63) == 0) smf[threadIdx.x >> 6] = s;
    __syncthreads();
    if (threadIdx.x == 0) {
        float tot = 0.f;
#pragma unroll
        for (int w = 0; w < 16; ++w) tot += smf[w];
        out[0] = tot * (1.0f / Bn);
    }
}

extern "C" void kernel_launch(void* const* d_in, const int* in_sizes, int n_in,
                              void* d_out, int out_size, void* d_ws, size_t ws_size,
                              hipStream_t stream)
{
    const float* x = (const float*)d_in[0];
    char* ws = (char*)d_ws;
    // workspace layout (bytes):
    uint8_t*  a_i8     = (uint8_t*)(ws + 0);         // 4 MB
    uint8_t*  p_i8     = (uint8_t*)(ws + 4194304);   // 4 MB
    float*    cterm    = (float*)(ws + 8388608);     // 32 KB
    float*    rowconst = (float*)(ws + 8421376);     // 32 KB
    unsigned* rowmax   = (unsigned*)(ws + 8454144);  // 32 KB (total ~8.5 MB)
    float*    out      = (float*)d_out;

    k_normalize<<<2048, 256, 0, stream>>>(x, a_i8, p_i8, cterm, rowconst, rowmax);
    k_gemm_argmax<<<dim3(NCT, Bn / BM), 256, 0, stream>>>(a_i8, p_i8, cterm, rowmax);
    k_final<<<1, 1024, 0, stream>>>(rowmax, rowconst, out);
}